// Round 8
// baseline (1105.140 us; speedup 1.0000x reference)
//
#include <hip/hip_runtime.h>
#include <hip/hip_fp16.h>
#include <cstdint>
#include <cstddef>

#define NN 100000
#define NE 800000
#define DIM 64
#define HEADS 4
#define HEAD_DIM 16
#define ALPHA 0.1f
#define K_ITERS 8
#define NBLK 391  // ceil(NN/256)
#define MAXD 64   // degree buckets for counting sort (deg clamped to 63)

typedef short bf16x8 __attribute__((ext_vector_type(8)));
typedef float f32x4 __attribute__((ext_vector_type(4)));

__device__ __forceinline__ unsigned short f2bf(float f) {
    unsigned int x = __float_as_uint(f);
    unsigned int r = (x + 0x7fffu + ((x >> 16) & 1u)) >> 16;  // RNE
    return (unsigned short)r;
}
__device__ __forceinline__ float bf_lo(unsigned int p) { return __uint_as_float(p << 16); }
__device__ __forceinline__ float bf_hi(unsigned int p) { return __uint_as_float(p & 0xffff0000u); }

__device__ __forceinline__ float2 h2f(unsigned int v) {
    __half2 h = *(__half2*)&v;
    return __half22float2(h);
}
__device__ __forceinline__ unsigned int f2h2(float a, float b) {
    __half2 h = __floats2half2_rn(a, b);
    return *(unsigned int*)&h;
}
__device__ __forceinline__ float dot8h(uint4 a, uint4 b) {
    float2 a0 = h2f(a.x), b0 = h2f(b.x);
    float2 a1 = h2f(a.y), b1 = h2f(b.y);
    float2 a2 = h2f(a.z), b2 = h2f(b.z);
    float2 a3 = h2f(a.w), b3 = h2f(b.w);
    return a0.x * b0.x + a0.y * b0.y + a1.x * b1.x + a1.y * b1.y
         + a2.x * b2.x + a2.y * b2.y + a3.x * b3.x + a3.y * b3.y;
}
__device__ __forceinline__ float dot4bf(float4 a, uint2 p) {
    return a.x * bf_lo(p.x) + a.y * bf_hi(p.x) + a.z * bf_lo(p.y) + a.w * bf_hi(p.y);
}

// NOTE: macro parameter must NOT be named 'z' (or x/y/w) — member tokens
// .x/.y/.z/.w would be substituted too.
#define ACC8(a, V) { float2 t_; \
    t_ = h2f((V).x); m[0] += (a) * t_.x; m[1] += (a) * t_.y; \
    t_ = h2f((V).y); m[2] += (a) * t_.x; m[3] += (a) * t_.y; \
    t_ = h2f((V).z); m[4] += (a) * t_.x; m[5] += (a) * t_.y; \
    t_ = h2f((V).w); m[6] += (a) * t_.x; m[7] += (a) * t_.y; }

// MFMA qkv+u: block = 64 nodes, 4 waves x 16 rows each. (See R7 notes.)
__global__ __launch_bounds__(256) void qkv_mfma_kernel(
    const float* __restrict__ x,
    const float* __restrict__ Wq, const float* __restrict__ Wk,
    const float* __restrict__ Wv, const float* __restrict__ We,
    __half* __restrict__ qh, __half* __restrict__ kh, __half* __restrict__ vh,
    unsigned short* __restrict__ u)
{
    __shared__ unsigned short sq[64 * 72];
    int tid = threadIdx.x;
    int w = tid >> 6;
    int lane = tid & 63;
    int m16 = lane & 15;
    int quad = lane >> 4;
    int node = blockIdx.x * 64 + w * 16 + m16;
    int nodeC = node < NN ? node : NN - 1;

    bf16x8 afrag[2];
    #pragma unroll
    for (int kk = 0; kk < 2; ++kk) {
        const float* xr = x + (size_t)nodeC * DIM + kk * 32 + quad * 8;
        #pragma unroll
        for (int j = 0; j < 8; ++j) afrag[kk][j] = (short)f2bf(xr[j]);
    }

    const float* Ws[3] = {Wq, Wk, Wv};
    __half* outs[3] = {qh, kh, vh};

    #pragma unroll
    for (int mtx = 0; mtx < 3; ++mtx) {
        const float* W = Ws[mtx];
        #pragma unroll
        for (int n0 = 0; n0 < 64; n0 += 16) {
            int col = n0 + m16;
            f32x4 acc = {0.f, 0.f, 0.f, 0.f};
            #pragma unroll
            for (int kk = 0; kk < 2; ++kk) {
                bf16x8 bfrag;
                #pragma unroll
                for (int j = 0; j < 8; ++j)
                    bfrag[j] = (short)f2bf(W[(kk * 32 + quad * 8 + j) * DIM + col]);
                acc = __builtin_amdgcn_mfma_f32_16x16x32_bf16(afrag[kk], bfrag, acc, 0, 0, 0);
            }
            if (mtx == 0) {
                #pragma unroll
                for (int r = 0; r < 4; ++r) acc[r] *= 0.25f;
            }
            #pragma unroll
            for (int r = 0; r < 4; ++r) {
                int rl = w * 16 + quad * 4 + r;
                int gnode = blockIdx.x * 64 + rl;
                if (mtx == 0) sq[rl * 72 + col] = f2bf(acc[r]);
                if (gnode < NN) outs[mtx][(size_t)gnode * DIM + col] = __float2half(acc[r]);
            }
        }
    }
    __syncthreads();

    #pragma unroll
    for (int h = 0; h < HEADS; ++h) {
        int kk = h >> 1;
        bf16x8 aq;
        const unsigned short* sr = &sq[(w * 16 + m16) * 72 + kk * 32 + quad * 8];
        #pragma unroll
        for (int j = 0; j < 8; ++j) aq[j] = (short)sr[j];
        #pragma unroll
        for (int c0 = 0; c0 < 64; c0 += 16) {
            int c = c0 + m16;
            bf16x8 bfrag;
            #pragma unroll
            for (int j = 0; j < 8; ++j) {
                int k = kk * 32 + quad * 8 + j;
                bfrag[j] = ((k >> 4) == h) ? (short)f2bf(We[c * DIM + k]) : (short)0;
            }
            f32x4 acc = {0.f, 0.f, 0.f, 0.f};
            acc = __builtin_amdgcn_mfma_f32_16x16x32_bf16(aq, bfrag, acc, 0, 0, 0);
            #pragma unroll
            for (int r = 0; r < 4; ++r) {
                int gnode = blockIdx.x * 64 + w * 16 + quad * 4 + r;
                if (gnode < NN) u[(size_t)gnode * 256 + h * 64 + c] = f2bf(acc[r]);
            }
        }
    }
}

__global__ void init_kernel(float* __restrict__ denom, int* __restrict__ deg,
                            int* __restrict__ hist) {
    int i = blockIdx.x * 256 + threadIdx.x;
    if (i < NN * HEADS) denom[i] = 0.f;
    if (i < NN) deg[i] = 0;
    if (i < MAXD) hist[i] = 0;
}

__global__ void deg_kernel(const int* __restrict__ ei, int* __restrict__ deg) {
    int e = blockIdx.x * 256 + threadIdx.x;
    if (e >= NE) return;
    atomicAdd(&deg[ei[NE + e]], 1);
}

__global__ void blocksum_kernel(const int* __restrict__ deg, int* __restrict__ bsum) {
    int t = threadIdx.x, b = blockIdx.x;
    int idx = b * 256 + t;
    int v = (idx < NN) ? deg[idx] : 0;
    #pragma unroll
    for (int off = 32; off > 0; off >>= 1) v += __shfl_down(v, off);
    __shared__ int wsum[4];
    if ((t & 63) == 0) wsum[t >> 6] = v;
    __syncthreads();
    if (t == 0) bsum[b] = wsum[0] + wsum[1] + wsum[2] + wsum[3];
}

__global__ void bscan_kernel(const int* __restrict__ bsum, int* __restrict__ boff) {
    __shared__ int s[512];
    int t = threadIdx.x;
    int v = (t < NBLK) ? bsum[t] : 0;
    s[t] = v;
    __syncthreads();
    for (int off = 1; off < 512; off <<= 1) {
        int u = (t >= off) ? s[t - off] : 0;
        __syncthreads();
        s[t] += u;
        __syncthreads();
    }
    if (t < NBLK) boff[t] = s[t] - v;
}

__global__ void rowptr_kernel(const int* __restrict__ deg, const int* __restrict__ boff,
                              int* __restrict__ row_ptr, int* __restrict__ cursor) {
    __shared__ int s[256];
    int t = threadIdx.x, b = blockIdx.x;
    int idx = b * 256 + t;
    int v = (idx < NN) ? deg[idx] : 0;
    s[t] = v;
    __syncthreads();
    for (int off = 1; off < 256; off <<= 1) {
        int u = (t >= off) ? s[t - off] : 0;
        __syncthreads();
        s[t] += u;
        __syncthreads();
    }
    if (idx < NN) {
        int ex = boff[b] + s[t] - v;
        row_ptr[idx] = ex;
        cursor[idx] = ex;
    }
    if (idx == 0) row_ptr[NN] = NE;
}

// ---- degree counting-sort: perm groups nodes of equal degree so the 8
// nodes sharing a prop wave have ~identical loop trip counts. ----
__global__ void dhist_kernel(const int* __restrict__ deg, int* __restrict__ hist) {
    __shared__ int lh[MAXD];
    int t = threadIdx.x;
    if (t < MAXD) lh[t] = 0;
    __syncthreads();
    int i = blockIdx.x * 256 + t;
    if (i < NN) atomicAdd(&lh[min(deg[i], MAXD - 1)], 1);
    __syncthreads();
    if (t < MAXD && lh[t]) atomicAdd(&hist[t], lh[t]);
}

__global__ void dscan_kernel(const int* __restrict__ hist, int* __restrict__ dcur) {
    int l = threadIdx.x;  // 0..63, one wave
    int v = hist[l];
    int s = v;
    #pragma unroll
    for (int off = 1; off < 64; off <<= 1) {
        int o = __shfl_up(s, off);
        if (l >= off) s += o;
    }
    dcur[l] = s - v;  // exclusive prefix
}

__global__ void dperm_kernel(const int* __restrict__ deg, int* __restrict__ dcur,
                             int* __restrict__ perm) {
    int i = blockIdx.x * 256 + threadIdx.x;
    if (i >= NN) return;
    int pos = atomicAdd(&dcur[min(deg[i], MAXD - 1)], 1);
    perm[pos] = i;
}

__global__ void scatter_kernel(const int* __restrict__ ei,
                               int* __restrict__ cursor,
                               int* __restrict__ csr_src,
                               int* __restrict__ csr_e,
                               int* __restrict__ csr_dst) {
    int e = blockIdx.x * 256 + threadIdx.x;
    if (e >= NE) return;
    int src = ei[e], dst = ei[NE + e];
    int pos = atomicAdd(&cursor[dst], 1);
    csr_src[pos] = src;
    csr_e[pos] = e;
    csr_dst[pos] = dst;
}

// CSR-order logits, wave-cooperative attr reads: wave = 16 slots; lane (r,c)
// r=lane>>4, c=lane&15. 16 lanes read one 256B attr row CONTIGUOUSLY (4 rows
// per instruction -> proper DRAM bursts). Each lane: dot4 partials for all 4
// heads vs u[dst]; shfl_xor reduce over c; lanes c<4 do qk+exp+atomic.
// NE % 64 == 0 so all slots valid (no tail).
__global__ void logits_csr_kernel(const __half* __restrict__ qh,
                                  const __half* __restrict__ kh,
                                  const float* __restrict__ edge_attr,
                                  const unsigned short* __restrict__ u,
                                  const int* __restrict__ csr_src,
                                  const int* __restrict__ csr_e,
                                  const int* __restrict__ csr_dst,
                                  __half* __restrict__ att,
                                  float* __restrict__ denom) {
    int wave = threadIdx.x >> 6;
    int lane = threadIdx.x & 63;
    int r = lane >> 4, c = lane & 15;
    int jbase = blockIdx.x * 64 + wave * 16;
    #pragma unroll
    for (int g = 0; g < 4; ++g) {
        int j = jbase + g * 4 + r;
        int e = csr_e[j], dst = csr_dst[j];
        float4 a4 = ((const float4*)edge_attr)[(size_t)e * 16 + c];
        const uint2* ub = (const uint2*)(u + (size_t)dst * 256);
        float4 au;
        au.x = dot4bf(a4, ub[0 * 16 + c]);
        au.y = dot4bf(a4, ub[1 * 16 + c]);
        au.z = dot4bf(a4, ub[2 * 16 + c]);
        au.w = dot4bf(a4, ub[3 * 16 + c]);
        #pragma unroll
        for (int msk = 8; msk >= 1; msk >>= 1) {
            au.x += __shfl_xor(au.x, msk);
            au.y += __shfl_xor(au.y, msk);
            au.z += __shfl_xor(au.z, msk);
            au.w += __shfl_xor(au.w, msk);
        }
        if (c < 4) {
            int h = c;
            float auh = (h == 0) ? au.x : (h == 1) ? au.y : (h == 2) ? au.z : au.w;
            int src = csr_src[j];
            const uint4* qq = (const uint4*)qh + (size_t)dst * 8 + h * 2;
            const uint4* kk = (const uint4*)kh + (size_t)src * 8 + h * 2;
            float qk = dot8h(qq[0], kk[0]) + dot8h(qq[1], kk[1]);
            float ex = __expf(qk + auh);  // logits bounded ~8; shift-invariant
            att[4 * j + h] = __float2half(ex);
            atomicAdd(&denom[dst * HEADS + h], ex);
        }
    }
}

// Propagation: 8 lanes/node, degree-sorted node order via perm.
// z_out = alpha*v + (0.9/denom) * sum_j ex_j * z[src_j]
__global__ void prop_csr_kernel(const __half* __restrict__ zin,
                                const __half* __restrict__ vh,
                                const __half* __restrict__ att,
                                const int* __restrict__ csr_src,
                                const int* __restrict__ row_ptr,
                                const float* __restrict__ denom,
                                const int* __restrict__ perm,
                                __half* __restrict__ zout) {
    int gid = blockIdx.x * 256 + threadIdx.x;
    int nidx = gid >> 3;
    if (nidx >= NN) return;
    int node = perm[nidx];
    int l = gid & 7;
    int head = l >> 1;
    const uint4* z4 = (const uint4*)zin;
    float m[8];
    #pragma unroll
    for (int i = 0; i < 8; ++i) m[i] = 0.f;
    int beg = row_ptr[node], end = row_ptr[node + 1];
    int j = beg;
    for (; j + 4 <= end; j += 4) {
        int s0 = csr_src[j], s1 = csr_src[j + 1], s2 = csr_src[j + 2], s3 = csr_src[j + 3];
        float a0 = __half2float(att[4 * j + head]);
        float a1 = __half2float(att[4 * j + 4 + head]);
        float a2 = __half2float(att[4 * j + 8 + head]);
        float a3 = __half2float(att[4 * j + 12 + head]);
        uint4 z0 = z4[(size_t)s0 * 8 + l];
        uint4 z1 = z4[(size_t)s1 * 8 + l];
        uint4 z2 = z4[(size_t)s2 * 8 + l];
        uint4 z3 = z4[(size_t)s3 * 8 + l];
        ACC8(a0, z0); ACC8(a1, z1); ACC8(a2, z2); ACC8(a3, z3);
    }
    for (; j < end; ++j) {
        int s = csr_src[j];
        float a = __half2float(att[4 * j + head]);
        uint4 zl = z4[(size_t)s * 8 + l];
        ACC8(a, zl);
    }
    float r = 0.9f / (denom[node * HEADS + head] + 1e-16f);
    uint4 vv = ((const uint4*)vh)[(size_t)node * 8 + l];
    float2 v0 = h2f(vv.x), v1 = h2f(vv.y), v2 = h2f(vv.z), v3 = h2f(vv.w);
    uint4 o;
    o.x = f2h2(ALPHA * v0.x + r * m[0], ALPHA * v0.y + r * m[1]);
    o.y = f2h2(ALPHA * v1.x + r * m[2], ALPHA * v1.y + r * m[3]);
    o.z = f2h2(ALPHA * v2.x + r * m[4], ALPHA * v2.y + r * m[5]);
    o.w = f2h2(ALPHA * v3.x + r * m[6], ALPHA * v3.y + r * m[7]);
    ((uint4*)zout)[(size_t)node * 8 + l] = o;
}

// Final iteration fused with epilogue: out = x + relu(z_new), fp32 out.
__global__ void prop_out_kernel(const __half* __restrict__ zin,
                                const __half* __restrict__ vh,
                                const __half* __restrict__ att,
                                const int* __restrict__ csr_src,
                                const int* __restrict__ row_ptr,
                                const float* __restrict__ denom,
                                const int* __restrict__ perm,
                                const float* __restrict__ x,
                                float* __restrict__ out) {
    int gid = blockIdx.x * 256 + threadIdx.x;
    int nidx = gid >> 3;
    if (nidx >= NN) return;
    int node = perm[nidx];
    int l = gid & 7;
    int head = l >> 1;
    const uint4* z4 = (const uint4*)zin;
    float m[8];
    #pragma unroll
    for (int i = 0; i < 8; ++i) m[i] = 0.f;
    int beg = row_ptr[node], end = row_ptr[node + 1];
    int j = beg;
    for (; j + 4 <= end; j += 4) {
        int s0 = csr_src[j], s1 = csr_src[j + 1], s2 = csr_src[j + 2], s3 = csr_src[j + 3];
        float a0 = __half2float(att[4 * j + head]);
        float a1 = __half2float(att[4 * j + 4 + head]);
        float a2 = __half2float(att[4 * j + 8 + head]);
        float a3 = __half2float(att[4 * j + 12 + head]);
        uint4 z0 = z4[(size_t)s0 * 8 + l];
        uint4 z1 = z4[(size_t)s1 * 8 + l];
        uint4 z2 = z4[(size_t)s2 * 8 + l];
        uint4 z3 = z4[(size_t)s3 * 8 + l];
        ACC8(a0, z0); ACC8(a1, z1); ACC8(a2, z2); ACC8(a3, z3);
    }
    for (; j < end; ++j) {
        int s = csr_src[j];
        float a = __half2float(att[4 * j + head]);
        uint4 zl = z4[(size_t)s * 8 + l];
        ACC8(a, zl);
    }
    float r = 0.9f / (denom[node * HEADS + head] + 1e-16f);
    uint4 vv = ((const uint4*)vh)[(size_t)node * 8 + l];
    float2 v0 = h2f(vv.x), v1 = h2f(vv.y), v2 = h2f(vv.z), v3 = h2f(vv.w);
    float zf[8] = { ALPHA * v0.x + r * m[0], ALPHA * v0.y + r * m[1],
                    ALPHA * v1.x + r * m[2], ALPHA * v1.y + r * m[3],
                    ALPHA * v2.x + r * m[4], ALPHA * v2.y + r * m[5],
                    ALPHA * v3.x + r * m[6], ALPHA * v3.y + r * m[7] };
    const float4* x4 = (const float4*)x + (size_t)node * 16 + l * 2;
    float4 xa = x4[0], xb = x4[1];
    float4 oa, ob;
    oa.x = xa.x + fmaxf(zf[0], 0.f); oa.y = xa.y + fmaxf(zf[1], 0.f);
    oa.z = xa.z + fmaxf(zf[2], 0.f); oa.w = xa.w + fmaxf(zf[3], 0.f);
    ob.x = xb.x + fmaxf(zf[4], 0.f); ob.y = xb.y + fmaxf(zf[5], 0.f);
    ob.z = xb.z + fmaxf(zf[6], 0.f); ob.w = xb.w + fmaxf(zf[7], 0.f);
    float4* o4 = (float4*)out + (size_t)node * 16 + l * 2;
    o4[0] = oa; o4[1] = ob;
}

extern "C" void kernel_launch(void* const* d_in, const int* in_sizes, int n_in,
                              void* d_out, int out_size, void* d_ws, size_t ws_size,
                              hipStream_t stream) {
    const float* x         = (const float*)d_in[0];
    const int*   ei        = (const int*)d_in[1];   // [2, NE]: row0=src, row1=dst
    const float* edge_attr = (const float*)d_in[2];
    const float* Wq        = (const float*)d_in[3];
    const float* Wk        = (const float*)d_in[4];
    const float* Wv        = (const float*)d_in[5];
    const float* We        = (const float*)d_in[6];
    float* out = (float*)d_out;

    __half* qh = (__half*)d_ws;                        // NN*64
    __half* kh = qh + (size_t)NN * DIM;                // NN*64
    __half* vh = kh + (size_t)NN * DIM;                // NN*64
    unsigned short* u = (unsigned short*)(vh + (size_t)NN * DIM);  // NN*256 bf16
    __half* zha = (__half*)(u + (size_t)NN * 256);     // NN*64
    __half* zhb = zha + (size_t)NN * DIM;              // NN*64
    __half* att = zhb + (size_t)NN * DIM;              // NE*4
    float* denom = (float*)(att + (size_t)NE * HEADS); // NN*4
    int* deg     = (int*)(denom + (size_t)NN * HEADS); // NN
    int* bsum    = deg + NN;                           // NBLK
    int* boff    = bsum + NBLK;                        // NBLK
    int* row_ptr = boff + NBLK;                        // NN+1
    int* cursor  = row_ptr + NN + 1;                   // NN
    int* csr_src = cursor + NN;                        // NE
    int* csr_e   = csr_src + NE;                       // NE
    int* csr_dst = csr_e + NE;                         // NE
    int* hist    = csr_dst + NE;                       // MAXD
    int* dcur    = hist + MAXD;                        // MAXD
    int* perm    = dcur + MAXD;                        // NN

    hipLaunchKernelGGL(qkv_mfma_kernel, dim3((NN + 63) / 64), dim3(256), 0, stream,
                       x, Wq, Wk, Wv, We, qh, kh, vh, u);
    hipLaunchKernelGGL(init_kernel, dim3((NN * HEADS + 255) / 256), dim3(256), 0, stream,
                       denom, deg, hist);
    hipLaunchKernelGGL(deg_kernel, dim3((NE + 255) / 256), dim3(256), 0, stream,
                       ei, deg);
    hipLaunchKernelGGL(blocksum_kernel, dim3(NBLK), dim3(256), 0, stream,
                       deg, bsum);
    hipLaunchKernelGGL(bscan_kernel, dim3(1), dim3(512), 0, stream,
                       bsum, boff);
    hipLaunchKernelGGL(rowptr_kernel, dim3(NBLK), dim3(256), 0, stream,
                       deg, boff, row_ptr, cursor);
    hipLaunchKernelGGL(dhist_kernel, dim3(NBLK), dim3(256), 0, stream,
                       deg, hist);
    hipLaunchKernelGGL(dscan_kernel, dim3(1), dim3(64), 0, stream,
                       hist, dcur);
    hipLaunchKernelGGL(dperm_kernel, dim3(NBLK), dim3(256), 0, stream,
                       deg, dcur, perm);
    hipLaunchKernelGGL(scatter_kernel, dim3((NE + 255) / 256), dim3(256), 0, stream,
                       ei, cursor, csr_src, csr_e, csr_dst);
    hipLaunchKernelGGL(logits_csr_kernel, dim3(NE / 64), dim3(256), 0, stream,
                       qh, kh, edge_attr, u, csr_src, csr_e, csr_dst, att, denom);

    const __half* zin = vh;
    __half* zout = zha;
    for (int it = 0; it < K_ITERS - 1; ++it) {
        hipLaunchKernelGGL(prop_csr_kernel, dim3((NN * 8 + 255) / 256), dim3(256), 0, stream,
                           zin, vh, att, csr_src, row_ptr, denom, perm, zout);
        zin = zout;
        zout = (zout == zha) ? zhb : zha;
    }
    hipLaunchKernelGGL(prop_out_kernel, dim3((NN * 8 + 255) / 256), dim3(256), 0, stream,
                       zin, vh, att, csr_src, row_ptr, denom, perm, x, out);
}